// Round 5
// baseline (787.088 us; speedup 1.0000x reference)
//
#include <hip/hip_runtime.h>

#define B_ROWS 8192
#define IN_DIM 2048
#define H_DIM  2048
#define K_DIM  4096              // IN + H
#define CH_OFF (B_ROWS * H_DIM)  // offset of h_t in d_out
#define NT     (K_DIM / 32)      // 128 K-tiles of depth 32

typedef __attribute__((ext_vector_type(8))) short bf16x8;
typedef __attribute__((ext_vector_type(8))) short short8;
typedef __attribute__((ext_vector_type(4))) float f32x4;

// fp32 -> bf16 round-to-nearest-even
static __device__ __forceinline__ unsigned short f2bf(float f) {
  union { float f; unsigned u; } v; v.f = f;
  unsigned r = v.u + 0x7fffu + ((v.u >> 16) & 1u);
  return (unsigned short)(r >> 16);
}

// async 16B global -> LDS (wave-uniform base + lane*16 on the LDS side)
static __device__ __forceinline__ void load_lds16(const void* g, void* l) {
  __builtin_amdgcn_global_load_lds(
      (const __attribute__((address_space(1))) unsigned int*)(unsigned long long)(uintptr_t)g,
      (__attribute__((address_space(3))) unsigned int*)(unsigned int)(uintptr_t)l,
      16, 0, 0);
}

// ---------------------------------------------------------------------------
// Pack [input | hidden] (fp32) -> A bf16 [8192][4096]
// ---------------------------------------------------------------------------
__global__ __launch_bounds__(256) void pack_act(
    const float* __restrict__ inp, const float* __restrict__ hid,
    short* __restrict__ out) {
  int idx = blockIdx.x * 256 + threadIdx.x;
  int m = idx >> 9;
  int k = (idx & 511) * 8;
  const float* s = (k < IN_DIM) ? (inp + m * IN_DIM + k)
                                : (hid + m * H_DIM + (k - IN_DIM));
  float4 a = *(const float4*)s;
  float4 c = *(const float4*)(s + 4);
  short8 o;
  o[0] = (short)f2bf(a.x); o[1] = (short)f2bf(a.y);
  o[2] = (short)f2bf(a.z); o[3] = (short)f2bf(a.w);
  o[4] = (short)f2bf(c.x); o[5] = (short)f2bf(c.y);
  o[6] = (short)f2bf(c.z); o[7] = (short)f2bf(c.w);
  *(short8*)(out + (size_t)idx * 8) = o;
}

// ---------------------------------------------------------------------------
// Pack + transpose weights -> WT[n][k] bf16, n = (h>>4)*64 + gate*16 + (h&15)
// ---------------------------------------------------------------------------
__global__ __launch_bounds__(256) void pack_w(
    const float* __restrict__ wi0, const float* __restrict__ wi1,
    const float* __restrict__ wi2, const float* __restrict__ wi3,
    const float* __restrict__ wh0, const float* __restrict__ wh1,
    const float* __restrict__ wh2, const float* __restrict__ wh3,
    short* __restrict__ out) {
  __shared__ float tileS[64][65];
  int b = blockIdx.x;
  int w = b >> 10;
  int tile = b & 1023;
  int tk = tile >> 5;
  int th = tile & 31;
  const float* src;
  switch (w) {
    case 0: src = wi0; break; case 1: src = wi1; break;
    case 2: src = wi2; break; case 3: src = wi3; break;
    case 4: src = wh0; break; case 5: src = wh1; break;
    case 6: src = wh2; break; default: src = wh3; break;
  }
  int g = w & 3, half = w >> 2;
  int t = threadIdx.x;
  #pragma unroll
  for (int it = 0; it < 4; ++it) {
    int idx = it * 256 + t;
    int sr = idx >> 4, sc = idx & 15;
    float4 v = *(const float4*)(src + (tk * 64 + sr) * H_DIM + th * 64 + sc * 4);
    tileS[sr][sc * 4 + 0] = v.x; tileS[sr][sc * 4 + 1] = v.y;
    tileS[sr][sc * 4 + 2] = v.z; tileS[sr][sc * 4 + 3] = v.w;
  }
  __syncthreads();
  #pragma unroll
  for (int it = 0; it < 2; ++it) {
    int idx = it * 256 + t;
    int orow = idx >> 3;
    int okg = idx & 7;
    short8 o;
    #pragma unroll
    for (int j = 0; j < 8; ++j) o[j] = (short)f2bf(tileS[okg * 8 + j][orow]);
    int hg = th * 64 + orow;
    int n = (hg >> 4) * 64 + g * 16 + (hg & 15);
    int off = n * K_DIM + half * IN_DIM + tk * 64 + okg * 8;
    *(short8*)(out + off) = o;
  }
}

// ---------------------------------------------------------------------------
// Fused GEMM (bf16 MFMA) + LSTM epilogue.
// 128x256 tile, 256 threads (4 waves, all-N split), 72 KB LDS (3-slot
// rotation) -> 2 blocks/CU. One barrier per K-tile, counted vmcnt(6).
// ---------------------------------------------------------------------------
__global__ __launch_bounds__(256, 2) void lstm_gemm(
    const short* __restrict__ actB,   // [8192][4096] bf16
    const short* __restrict__ wB,     // [8192][4096] bf16 packed W^T
    const float* __restrict__ cprev,
    const float* __restrict__ bi_p, const float* __restrict__ bf_p,
    const float* __restrict__ bg_p, const float* __restrict__ bo_p,
    float* __restrict__ out) {
  // slot: row-major [rows][32k], 4 chunks of 16B per 64B row, chunk XOR-
  // swizzled with (row>>1)&3 (conflict-free at 8-lane granularity).
  __shared__ __align__(16) short As[3][4096];   // 24 KB (slot 8 KB, 128 rows)
  __shared__ __align__(16) short Bs[3][8192];   // 48 KB (slot 16 KB, 256 rows)

  int bid = blockIdx.x;
  int swz = (bid & 7) * 256 + (bid >> 3);   // bijective XCD swizzle (2048%8==0)
  int mblk = swz >> 5, nblk = swz & 31;     // 64 m-blocks x 32 n-blocks
  int m0 = mblk * 128;
  int n0 = nblk * 256;

  int t = threadIdx.x;                      // 0..255
  int lane = t & 63, wn = t >> 6;           // 4 waves, all-N split
  int q = lane >> 4, cl = lane & 15;

  // --- staging: per thread 2 A-chunks + 4 B-chunks per K-tile (16B each) ---
  const short* aSrc[2]; char* aDst[2];
  const short* bSrc[4]; char* bDst[4];
  #pragma unroll
  for (int it = 0; it < 2; ++it) {
    int idx = it * 256 + t;                 // 0..511
    int rp = idx >> 2, c = idx & 3;
    int cu = c ^ ((rp >> 1) & 3);           // logical k-octet at this phys pos
    aSrc[it] = actB + (size_t)(m0 + rp) * K_DIM + cu * 8;
    aDst[it] = (char*)&As[0][0] + idx * 16;
  }
  #pragma unroll
  for (int it = 0; it < 4; ++it) {
    int idx = it * 256 + t;                 // 0..1023
    int rp = idx >> 2, c = idx & 3;
    int cu = c ^ ((rp >> 1) & 3);
    bSrc[it] = wB + (size_t)(n0 + rp) * K_DIM + cu * 8;
    bDst[it] = (char*)&Bs[0][0] + idx * 16;
  }

  // --- fragment read bases: phys chunk = q ^ ((cl>>1)&3), row stride 64B ---
  int pc = (q ^ ((cl >> 1) & 3)) * 16;
  const char* aRd = (const char*)&As[0][0] + cl * 64 + pc;
  const char* bRd = (const char*)&Bs[0][0] + (wn * 64 + cl) * 64 + pc;

  f32x4 zero = {0.f, 0.f, 0.f, 0.f};
  f32x4 acc[8][4];
  #pragma unroll
  for (int mi = 0; mi < 8; ++mi)
    #pragma unroll
    for (int ni = 0; ni < 4; ++ni) acc[mi][ni] = zero;

  // prologue: stage tiles 0 (slot0) and 1 (slot1); publish tile 0
  #pragma unroll
  for (int p = 0; p < 2; ++p) {
    int koB = p * 64;                        // k-byte offset of tile p
    int sA = p * 8192, sB = p * 16384;
    load_lds16((const char*)aSrc[0] + koB, aDst[0] + sA);
    load_lds16((const char*)aSrc[1] + koB, aDst[1] + sA);
    #pragma unroll
    for (int it = 0; it < 4; ++it)
      load_lds16((const char*)bSrc[it] + koB, bDst[it] + sB);
  }
  asm volatile("s_waitcnt vmcnt(6)" ::: "memory");   // tile 0 landed
  __builtin_amdgcn_s_barrier();

  int slA = 0, slB = 0;                     // byte offset of slot kt%3
  int stA = 2 * 8192, stB = 2 * 16384;      // byte offset of slot (kt+2)%3

  #pragma unroll 1
  for (int kt = 0; kt < NT; ++kt) {
    // ---- frag reads from slot kt%3 ----
    bf16x8 aF[8], bF[4];
    #pragma unroll
    for (int mi = 0; mi < 8; ++mi)
      aF[mi] = *(const bf16x8*)(aRd + slA + mi * 1024);
    #pragma unroll
    for (int ni = 0; ni < 4; ++ni)
      bF[ni] = *(const bf16x8*)(bRd + slB + ni * 1024);
    // ---- stage tile kt+2 into rolling slot (clamped at tail; WAR-safe) ----
    int kst = kt + 2; if (kst > NT - 1) kst = NT - 1;
    int koB = kst * 64;
    load_lds16((const char*)aSrc[0] + koB, aDst[0] + stA);
    load_lds16((const char*)aSrc[1] + koB, aDst[1] + stA);
    #pragma unroll
    for (int it = 0; it < 4; ++it)
      load_lds16((const char*)bSrc[it] + koB, bDst[it] + stB);
    // ---- MFMA (consumes frag reads; compiler inserts lgkm waits) ----
    __builtin_amdgcn_s_setprio(1);
    #pragma unroll
    for (int mi = 0; mi < 8; ++mi)
      #pragma unroll
      for (int ni = 0; ni < 4; ++ni)
        acc[mi][ni] = __builtin_amdgcn_mfma_f32_16x16x32_bf16(
            aF[mi], bF[ni], acc[mi][ni], 0, 0, 0);
    __builtin_amdgcn_s_setprio(0);
    // ---- publish tile kt+1 (counted, never 0) and close the iteration ----
    asm volatile("s_waitcnt vmcnt(6)" ::: "memory");
    __builtin_amdgcn_sched_barrier(0);       // pin: nothing crosses the fence
    __builtin_amdgcn_s_barrier();
    slA = (slA == 16384) ? 0 : slA + 8192;
    slB = (slB == 32768) ? 0 : slB + 16384;
    stA = (stA == 16384) ? 0 : stA + 8192;
    stB = (stB == 32768) ? 0 : stB + 16384;
  }
  // retire in-flight garbage stages before epilogue
  asm volatile("s_waitcnt vmcnt(0)" ::: "memory");

  // ---- epilogue: each lane holds i,f,g,o for the same (row, h) ----
  int hg = (nblk * 4 + wn) * 16 + cl;
  float vbi = bi_p[hg], vbf = bf_p[hg], vbg = bg_p[hg], vbo = bo_p[hg];
  #pragma unroll
  for (int mi = 0; mi < 8; ++mi) {
    #pragma unroll
    for (int r = 0; r < 4; ++r) {
      int mg = m0 + mi * 16 + q * 4 + r;
      float pi = acc[mi][0][r] + vbi;
      float pf = acc[mi][1][r] + vbf;
      float pg = acc[mi][2][r] + vbg;
      float po = acc[mi][3][r] + vbo;
      float iv = 1.f / (1.f + __expf(-pi));
      float fv = 1.f / (1.f + __expf(-pf));
      float gv = 1.f - 2.f / (__expf(2.f * pg) + 1.f);
      float ov = 1.f / (1.f + __expf(-po));
      float cp = cprev[(size_t)mg * H_DIM + hg];
      float cv = fv * cp + iv * gv;
      float tc = 1.f - 2.f / (__expf(2.f * cv) + 1.f);
      out[(size_t)mg * H_DIM + hg] = cv;
      out[CH_OFF + (size_t)mg * H_DIM + hg] = ov * tc;
    }
  }
}

extern "C" void kernel_launch(void* const* d_in, const int* in_sizes, int n_in,
                              void* d_out, int out_size, void* d_ws, size_t ws_size,
                              hipStream_t stream) {
  const float* inp   = (const float*)d_in[0];
  const float* hid   = (const float*)d_in[1];
  const float* cprev = (const float*)d_in[2];
  short* actB = (short*)d_ws;
  short* wB   = actB + (size_t)B_ROWS * K_DIM;

  pack_act<<<dim3(B_ROWS * K_DIM / 8 / 256), dim3(256), 0, stream>>>(inp, hid, actB);
  pack_w<<<dim3(8 * 1024), dim3(256), 0, stream>>>(
      (const float*)d_in[3], (const float*)d_in[4],
      (const float*)d_in[5], (const float*)d_in[6],
      (const float*)d_in[7], (const float*)d_in[8],
      (const float*)d_in[9], (const float*)d_in[10], wB);
  lstm_gemm<<<dim3(2048), dim3(256), 0, stream>>>(
      actB, wB, cprev,
      (const float*)d_in[11], (const float*)d_in[12],
      (const float*)d_in[13], (const float*)d_in[14],
      (float*)d_out);
}

// Round 6
// 560.736 us; speedup vs baseline: 1.4037x; 1.4037x over previous
//
#include <hip/hip_runtime.h>

#define B_ROWS 8192
#define IN_DIM 2048
#define H_DIM  2048
#define K_DIM  4096              // IN + H
#define CH_OFF (B_ROWS * H_DIM)  // offset of h_t in d_out
#define NKS    (K_DIM / 64)      // 64 K-steps of depth 64
#define NIT    (NKS / 2)         // 32 iterations, 2 K-steps each

typedef __attribute__((ext_vector_type(8))) short bf16x8;
typedef __attribute__((ext_vector_type(8))) short short8;
typedef __attribute__((ext_vector_type(4))) float f32x4;

// fp32 -> bf16 round-to-nearest-even
static __device__ __forceinline__ unsigned short f2bf(float f) {
  union { float f; unsigned u; } v; v.f = f;
  unsigned r = v.u + 0x7fffu + ((v.u >> 16) & 1u);
  return (unsigned short)(r >> 16);
}

// async 16B global -> LDS (wave-uniform base + lane*16 on the LDS side)
static __device__ __forceinline__ void load_lds16(const void* g, void* l) {
  __builtin_amdgcn_global_load_lds(
      (const __attribute__((address_space(1))) unsigned int*)(unsigned long long)(uintptr_t)g,
      (__attribute__((address_space(3))) unsigned int*)(unsigned int)(uintptr_t)l,
      16, 0, 0);
}

// ---------------------------------------------------------------------------
// Pack [input | hidden] (fp32) -> A bf16 [8192][4096]
// ---------------------------------------------------------------------------
__global__ __launch_bounds__(256) void pack_act(
    const float* __restrict__ inp, const float* __restrict__ hid,
    short* __restrict__ out) {
  int idx = blockIdx.x * 256 + threadIdx.x;
  int m = idx >> 9;
  int k = (idx & 511) * 8;
  const float* s = (k < IN_DIM) ? (inp + m * IN_DIM + k)
                                : (hid + m * H_DIM + (k - IN_DIM));
  float4 a = *(const float4*)s;
  float4 c = *(const float4*)(s + 4);
  short8 o;
  o[0] = (short)f2bf(a.x); o[1] = (short)f2bf(a.y);
  o[2] = (short)f2bf(a.z); o[3] = (short)f2bf(a.w);
  o[4] = (short)f2bf(c.x); o[5] = (short)f2bf(c.y);
  o[6] = (short)f2bf(c.z); o[7] = (short)f2bf(c.w);
  *(short8*)(out + (size_t)idx * 8) = o;
}

// ---------------------------------------------------------------------------
// Pack + transpose weights -> WT[n][k] bf16, n = (h>>4)*64 + gate*16 + (h&15)
// ---------------------------------------------------------------------------
__global__ __launch_bounds__(256) void pack_w(
    const float* __restrict__ wi0, const float* __restrict__ wi1,
    const float* __restrict__ wi2, const float* __restrict__ wi3,
    const float* __restrict__ wh0, const float* __restrict__ wh1,
    const float* __restrict__ wh2, const float* __restrict__ wh3,
    short* __restrict__ out) {
  __shared__ float tileS[64][65];
  int b = blockIdx.x;
  int w = b >> 10;
  int tile = b & 1023;
  int tk = tile >> 5;
  int th = tile & 31;
  const float* src;
  switch (w) {
    case 0: src = wi0; break; case 1: src = wi1; break;
    case 2: src = wi2; break; case 3: src = wi3; break;
    case 4: src = wh0; break; case 5: src = wh1; break;
    case 6: src = wh2; break; default: src = wh3; break;
  }
  int g = w & 3, half = w >> 2;
  int t = threadIdx.x;
  #pragma unroll
  for (int it = 0; it < 4; ++it) {
    int idx = it * 256 + t;
    int sr = idx >> 4, sc = idx & 15;
    float4 v = *(const float4*)(src + (tk * 64 + sr) * H_DIM + th * 64 + sc * 4);
    tileS[sr][sc * 4 + 0] = v.x; tileS[sr][sc * 4 + 1] = v.y;
    tileS[sr][sc * 4 + 2] = v.z; tileS[sr][sc * 4 + 3] = v.w;
  }
  __syncthreads();
  #pragma unroll
  for (int it = 0; it < 2; ++it) {
    int idx = it * 256 + t;
    int orow = idx >> 3;
    int okg = idx & 7;
    short8 o;
    #pragma unroll
    for (int j = 0; j < 8; ++j) o[j] = (short)f2bf(tileS[okg * 8 + j][orow]);
    int hg = th * 64 + orow;
    int n = (hg >> 4) * 64 + g * 16 + (hg & 15);
    int off = n * K_DIM + half * IN_DIM + tk * 64 + okg * 8;
    *(short8*)(out + off) = o;
  }
}

// ---------------------------------------------------------------------------
// Fused GEMM (bf16 MFMA) + LSTM epilogue — m201 8-phase quadrant schedule.
// 256x256 tile, BK=64, 2-buf LDS (128 KB), 8 waves (2M x 4N).
// Per K-step: 4 phases = C-quadrants Q00->Q01->Q11->Q10 with operand reuse;
// per phase: {ds_reads (12/4/8/0); stage 1 half-tile; [lgkm8|vmcnt4]; bar;
//             lgkm0; sched_barrier; prio1; 16 MFMA; prio0; bar}.
// ---------------------------------------------------------------------------
__global__ __launch_bounds__(512, 2) void lstm_gemm(
    const short* __restrict__ actB,   // [8192][4096] bf16
    const short* __restrict__ wB,     // [8192][4096] bf16 packed W^T
    const float* __restrict__ cprev,
    const float* __restrict__ bi_p, const float* __restrict__ bf_p,
    const float* __restrict__ bg_p, const float* __restrict__ bo_p,
    float* __restrict__ out) {
  // buf: 256 rows x 64 k x 2B = 32 KB; row = 128B = 8 chunks of 16B,
  // phys chunk = logical ^ (row & 7). 2 bufs per operand.
  __shared__ __align__(16) short As[2][16384];   // 64 KB
  __shared__ __align__(16) short Bs[2][16384];   // 64 KB

  int bid = blockIdx.x;
  int swz = (bid & 7) * 128 + (bid >> 3);   // bijective XCD swizzle (1024%8==0)
  int mblk = swz >> 5, nblk = swz & 31;
  int m0 = mblk * 256;
  int n0 = nblk * 256;

  int t = threadIdx.x;
  int lane = t & 63, wid = t >> 6;
  int wm = wid >> 2, wn = wid & 3;          // 2M x 4N wave grid
  int q = lane >> 4, cl = lane & 15;

  // ---- staging thread map: idx = ld*512+t covers one half-tile (128r x 8c)
  int rpl0 = t >> 3, c0s = t & 7;
  int cu0 = c0s ^ (rpl0 & 7);
  int idx1 = 512 + t;
  int rpl1 = idx1 >> 3, c1s = idx1 & 7;
  int cu1 = c1s ^ (rpl1 & 7);
  const short* aG0 = actB + (size_t)(m0 + rpl0) * K_DIM + cu0 * 8;
  const short* aG1 = actB + (size_t)(m0 + rpl1) * K_DIM + cu1 * 8;
  const short* bG0 = wB   + (size_t)(n0 + rpl0) * K_DIM + cu0 * 8;
  const short* bG1 = wB   + (size_t)(n0 + rpl1) * K_DIM + cu1 * 8;
  char* aL0 = (char*)&As[0][0] + t * 16;
  char* aL1 = (char*)&As[0][0] + idx1 * 16;
  char* bL0 = (char*)&Bs[0][0] + t * 16;
  char* bL1 = (char*)&Bs[0][0] + idx1 * 16;

  auto stgA = [&](int ks, int h, int buf) {   // h,buf compile-time at call
    load_lds16(aG0 + h * (128 * K_DIM) + ks * 64, aL0 + buf * 32768 + h * 16384);
    load_lds16(aG1 + h * (128 * K_DIM) + ks * 64, aL1 + buf * 32768 + h * 16384);
  };
  auto stgB = [&](int ks, int h, int buf) {
    load_lds16(bG0 + h * (128 * K_DIM) + ks * 64, bL0 + buf * 32768 + h * 16384);
    load_lds16(bG1 + h * (128 * K_DIM) + ks * 64, bL1 + buf * 32768 + h * 16384);
  };

  // ---- fragment read bases: row r byte = r*128, chunk = (s*4+q)^(r&7) ----
  int cc0 = (q ^ (cl & 7)) * 16;
  const char* aRd0 = (const char*)&As[0][0] + wm * 16384 + cl * 128 + cc0;
  const char* aRd1 = (const char*)&As[0][0] + wm * 16384 + cl * 128 + (cc0 ^ 64);
  const char* bRd0 = (const char*)&Bs[0][0] + wn * 8192 + cl * 128 + cc0;
  const char* bRd1 = (const char*)&Bs[0][0] + wn * 8192 + cl * 128 + (cc0 ^ 64);

  auto rdA = [&](int buf, int mi, int s) -> bf16x8 {   // all args compile-time
    return *(const bf16x8*)((s ? aRd1 : aRd0) + buf * 32768 + mi * 2048);
  };
  auto rdB = [&](int buf, int ni, int s) -> bf16x8 {
    return *(const bf16x8*)((s ? bRd1 : bRd0) + buf * 32768 + ni * 2048);
  };

  f32x4 zero = {0.f, 0.f, 0.f, 0.f};
  f32x4 acc[8][4];
  #pragma unroll
  for (int mi = 0; mi < 8; ++mi)
    #pragma unroll
    for (int ni = 0; ni < 4; ++ni) acc[mi][ni] = zero;

  bf16x8 aLo[4][2], aHi[4][2], b0f[2][2], b1f[2][2];

  auto QUAD = [&](bf16x8 (&af)[4][2], bf16x8 (&bf)[2][2], int mb, int nb) {
    __builtin_amdgcn_s_setprio(1);
    #pragma unroll
    for (int mi = 0; mi < 4; ++mi)
      #pragma unroll
      for (int ni = 0; ni < 2; ++ni)
        #pragma unroll
        for (int s = 0; s < 2; ++s)
          acc[mb + mi][nb + ni] = __builtin_amdgcn_mfma_f32_16x16x32_bf16(
              af[mi][s], bf[ni][s], acc[mb + mi][nb + ni], 0, 0, 0);
    __builtin_amdgcn_s_setprio(0);
  };

  // one K-step (4 phases). bufC = current buffer; stages: A(ksA_->bufA_),
  // B(ksB_->bufB_), one half-tile per phase, as-early-as-WAR-safe.
  auto halfK = [&](int bufC, int ksA_, int bufA_, int ksB_, int bufB_) {
    // -- P_a: read A-lo(8) + B0(4); stage A-h0; Q00 --
    #pragma unroll
    for (int mi = 0; mi < 4; ++mi) {
      aLo[mi][0] = rdA(bufC, mi, 0); aLo[mi][1] = rdA(bufC, mi, 1);
    }
    #pragma unroll
    for (int ni = 0; ni < 2; ++ni) {
      b0f[ni][0] = rdB(bufC, ni, 0); b0f[ni][1] = rdB(bufC, ni, 1);
    }
    stgA(ksA_, 0, bufA_);
    asm volatile("s_waitcnt lgkmcnt(8)" ::: "memory");
    __builtin_amdgcn_s_barrier();
    asm volatile("s_waitcnt lgkmcnt(0)" ::: "memory");
    __builtin_amdgcn_sched_barrier(0);
    QUAD(aLo, b0f, 0, 0);
    __builtin_amdgcn_s_barrier();
    // -- P_b: read B1(4); stage A-h1; Q01 --
    #pragma unroll
    for (int ni = 0; ni < 2; ++ni) {
      b1f[ni][0] = rdB(bufC, ni + 2, 0); b1f[ni][1] = rdB(bufC, ni + 2, 1);
    }
    stgA(ksA_, 1, bufA_);
    __builtin_amdgcn_s_barrier();
    asm volatile("s_waitcnt lgkmcnt(0)" ::: "memory");
    __builtin_amdgcn_sched_barrier(0);
    QUAD(aLo, b1f, 0, 2);
    __builtin_amdgcn_s_barrier();
    // -- P_c: read A-hi(8); stage B-h0; Q11 --
    #pragma unroll
    for (int mi = 0; mi < 4; ++mi) {
      aHi[mi][0] = rdA(bufC, mi + 4, 0); aHi[mi][1] = rdA(bufC, mi + 4, 1);
    }
    stgB(ksB_, 0, bufB_);
    __builtin_amdgcn_s_barrier();
    asm volatile("s_waitcnt lgkmcnt(0)" ::: "memory");
    __builtin_amdgcn_sched_barrier(0);
    QUAD(aHi, b1f, 4, 2);
    __builtin_amdgcn_s_barrier();
    // -- P_d: no reads; stage B-h1; vmcnt(4); Q10 --
    stgB(ksB_, 1, bufB_);
    asm volatile("s_waitcnt vmcnt(4)" ::: "memory");
    __builtin_amdgcn_s_barrier();
    __builtin_amdgcn_sched_barrier(0);
    QUAD(aHi, b0f, 4, 0);
    __builtin_amdgcn_s_barrier();
  };

  // prologue = virtual prev-iteration P3..P8: B(0), A(0), B(1); drain 8 oldest
  stgB(0, 0, 0); stgB(0, 1, 0);
  stgA(0, 0, 0); stgA(0, 1, 0);
  stgB(1, 0, 1); stgB(1, 1, 1);
  asm volatile("s_waitcnt vmcnt(4)" ::: "memory");
  __builtin_amdgcn_s_barrier();

  #pragma unroll 1
  for (int i = 0; i < NIT; ++i) {
    int ks1 = 2 * i + 1;
    int ksA = 2 * i + 2; if (ksA > NKS - 1) ksA = NKS - 1;
    int ksB = 2 * i + 3; if (ksB > NKS - 1) ksB = NKS - 1;
    halfK(0, ks1, 1, ksA, 0);   // K-step 2i   (buf0); stage A(2i+1), B(2i+2)
    halfK(1, ksA, 0, ksB, 1);   // K-step 2i+1 (buf1); stage A(2i+2), B(2i+3)
  }
  asm volatile("s_waitcnt vmcnt(0)" ::: "memory");

  // ---- epilogue: each lane holds i,f,g,o for the same (row, h) ----
  int hg = (nblk * 4 + wn) * 16 + cl;
  float vbi = bi_p[hg], vbf = bf_p[hg], vbg = bg_p[hg], vbo = bo_p[hg];
  int mbase = m0 + wm * 128;
  #pragma unroll
  for (int mi = 0; mi < 8; ++mi) {
    #pragma unroll
    for (int r = 0; r < 4; ++r) {
      int mg = mbase + mi * 16 + q * 4 + r;
      float pi = acc[mi][0][r] + vbi;
      float pf = acc[mi][1][r] + vbf;
      float pg = acc[mi][2][r] + vbg;
      float po = acc[mi][3][r] + vbo;
      float iv = 1.f / (1.f + __expf(-pi));
      float fv = 1.f / (1.f + __expf(-pf));
      float gv = 1.f - 2.f / (__expf(2.f * pg) + 1.f);
      float ov = 1.f / (1.f + __expf(-po));
      float cp = cprev[(size_t)mg * H_DIM + hg];
      float cv = fv * cp + iv * gv;
      float tc = 1.f - 2.f / (__expf(2.f * cv) + 1.f);
      out[(size_t)mg * H_DIM + hg] = cv;
      out[CH_OFF + (size_t)mg * H_DIM + hg] = ov * tc;
    }
  }
}

extern "C" void kernel_launch(void* const* d_in, const int* in_sizes, int n_in,
                              void* d_out, int out_size, void* d_ws, size_t ws_size,
                              hipStream_t stream) {
  const float* inp   = (const float*)d_in[0];
  const float* hid   = (const float*)d_in[1];
  const float* cprev = (const float*)d_in[2];
  short* actB = (short*)d_ws;
  short* wB   = actB + (size_t)B_ROWS * K_DIM;

  pack_act<<<dim3(B_ROWS * K_DIM / 8 / 256), dim3(256), 0, stream>>>(inp, hid, actB);
  pack_w<<<dim3(8 * 1024), dim3(256), 0, stream>>>(
      (const float*)d_in[3], (const float*)d_in[4],
      (const float*)d_in[5], (const float*)d_in[6],
      (const float*)d_in[7], (const float*)d_in[8],
      (const float*)d_in[9], (const float*)d_in[10], wB);
  lstm_gemm<<<dim3(1024), dim3(512), 0, stream>>>(
      actB, wB, cprev,
      (const float*)d_in[11], (const float*)d_in[12],
      (const float*)d_in[13], (const float*)d_in[14],
      (float*)d_out);
}

// Round 10
// 560.548 us; speedup vs baseline: 1.4041x; 1.0003x over previous
//
#include <hip/hip_runtime.h>

#define B_ROWS 8192
#define IN_DIM 2048
#define H_DIM  2048
#define K_DIM  4096              // IN + H
#define CH_OFF (B_ROWS * H_DIM)  // offset of h_t in d_out
#define NKS    (K_DIM / 64)      // 64 K-steps of depth 64
#define NIT    (NKS / 2)         // 32 iterations, 2 K-steps each

typedef __attribute__((ext_vector_type(8))) short bf16x8;
typedef __attribute__((ext_vector_type(8))) short short8;
typedef __attribute__((ext_vector_type(4))) float f32x4;

// fp32 -> bf16 round-to-nearest-even
static __device__ __forceinline__ unsigned short f2bf(float f) {
  union { float f; unsigned u; } v; v.f = f;
  unsigned r = v.u + 0x7fffu + ((v.u >> 16) & 1u);
  return (unsigned short)(r >> 16);
}

// async 16B global -> LDS (wave-uniform base + lane*16 on the LDS side).
// NOTE: offset operand MUST be 0 — non-zero offsets produced wrong LDS
// contents on gfx950 (R7/R8/R9 NaNs; only offset=0 is HW-verified).
static __device__ __forceinline__ void load_lds16(const void* g, void* l) {
  __builtin_amdgcn_global_load_lds(
      (const __attribute__((address_space(1))) unsigned int*)(unsigned long long)(uintptr_t)g,
      (__attribute__((address_space(3))) unsigned int*)(unsigned int)(uintptr_t)l,
      16, 0, 0);
}

// ---------------------------------------------------------------------------
// Pack [input | hidden] (fp32) -> A bf16 [8192][4096]
// ---------------------------------------------------------------------------
__global__ __launch_bounds__(256) void pack_act(
    const float* __restrict__ inp, const float* __restrict__ hid,
    short* __restrict__ out) {
  int idx = blockIdx.x * 256 + threadIdx.x;
  int m = idx >> 9;
  int k = (idx & 511) * 8;
  const float* s = (k < IN_DIM) ? (inp + m * IN_DIM + k)
                                : (hid + m * H_DIM + (k - IN_DIM));
  float4 a = *(const float4*)s;
  float4 c = *(const float4*)(s + 4);
  short8 o;
  o[0] = (short)f2bf(a.x); o[1] = (short)f2bf(a.y);
  o[2] = (short)f2bf(a.z); o[3] = (short)f2bf(a.w);
  o[4] = (short)f2bf(c.x); o[5] = (short)f2bf(c.y);
  o[6] = (short)f2bf(c.z); o[7] = (short)f2bf(c.w);
  *(short8*)(out + (size_t)idx * 8) = o;
}

// ---------------------------------------------------------------------------
// Pack + transpose weights -> WT[n][k] bf16, n = (h>>4)*64 + gate*16 + (h&15)
// ---------------------------------------------------------------------------
__global__ __launch_bounds__(256) void pack_w(
    const float* __restrict__ wi0, const float* __restrict__ wi1,
    const float* __restrict__ wi2, const float* __restrict__ wi3,
    const float* __restrict__ wh0, const float* __restrict__ wh1,
    const float* __restrict__ wh2, const float* __restrict__ wh3,
    short* __restrict__ out) {
  __shared__ float tileS[64][65];
  int b = blockIdx.x;
  int w = b >> 10;
  int tile = b & 1023;
  int tk = tile >> 5;
  int th = tile & 31;
  const float* src;
  switch (w) {
    case 0: src = wi0; break; case 1: src = wi1; break;
    case 2: src = wi2; break; case 3: src = wi3; break;
    case 4: src = wh0; break; case 5: src = wh1; break;
    case 6: src = wh2; break; default: src = wh3; break;
  }
  int g = w & 3, half = w >> 2;
  int t = threadIdx.x;
  #pragma unroll
  for (int it = 0; it < 4; ++it) {
    int idx = it * 256 + t;
    int sr = idx >> 4, sc = idx & 15;
    float4 v = *(const float4*)(src + (tk * 64 + sr) * H_DIM + th * 64 + sc * 4);
    tileS[sr][sc * 4 + 0] = v.x; tileS[sr][sc * 4 + 1] = v.y;
    tileS[sr][sc * 4 + 2] = v.z; tileS[sr][sc * 4 + 3] = v.w;
  }
  __syncthreads();
  #pragma unroll
  for (int it = 0; it < 2; ++it) {
    int idx = it * 256 + t;
    int orow = idx >> 3;
    int okg = idx & 7;
    short8 o;
    #pragma unroll
    for (int j = 0; j < 8; ++j) o[j] = (short)f2bf(tileS[okg * 8 + j][orow]);
    int hg = th * 64 + orow;
    int n = (hg >> 4) * 64 + g * 16 + (hg & 15);
    int off = n * K_DIM + half * IN_DIM + tk * 64 + okg * 8;
    *(short8*)(out + off) = o;
  }
}

// ---------------------------------------------------------------------------
// Fused GEMM (bf16 MFMA) + LSTM epilogue — R6's 8-phase quadrant schedule
// with ONE edit: b0-frag reads moved from P_a into the previous P_d (after
// Q10), balancing per-phase ds_reads to {8,4,8,4}.
// ---------------------------------------------------------------------------
__global__ __launch_bounds__(512, 2) void lstm_gemm(
    const short* __restrict__ actB,   // [8192][4096] bf16
    const short* __restrict__ wB,     // [8192][4096] bf16 packed W^T
    const float* __restrict__ cprev,
    const float* __restrict__ bi_p, const float* __restrict__ bf_p,
    const float* __restrict__ bg_p, const float* __restrict__ bo_p,
    float* __restrict__ out) {
  // buf: 256 rows x 64 k x 2B = 32 KB; row = 128B = 8 chunks of 16B,
  // phys chunk = logical ^ (row & 7). 2 bufs per operand.
  __shared__ __align__(16) short As[2][16384];   // 64 KB
  __shared__ __align__(16) short Bs[2][16384];   // 64 KB

  int bid = blockIdx.x;
  int swz = (bid & 7) * 128 + (bid >> 3);   // bijective XCD swizzle (1024%8==0)
  int mblk = swz >> 5, nblk = swz & 31;
  int m0 = mblk * 256;
  int n0 = nblk * 256;

  int t = threadIdx.x;
  int lane = t & 63, wid = t >> 6;
  int wm = wid >> 2, wn = wid & 3;          // 2M x 4N wave grid
  int q = lane >> 4, cl = lane & 15;

  // ---- staging thread map: idx = ld*512+t covers one half-tile (128r x 8c)
  int rpl0 = t >> 3, c0s = t & 7;
  int cu0 = c0s ^ (rpl0 & 7);
  int idx1 = 512 + t;
  int rpl1 = idx1 >> 3, c1s = idx1 & 7;
  int cu1 = c1s ^ (rpl1 & 7);
  const short* aG0 = actB + (size_t)(m0 + rpl0) * K_DIM + cu0 * 8;
  const short* aG1 = actB + (size_t)(m0 + rpl1) * K_DIM + cu1 * 8;
  const short* bG0 = wB   + (size_t)(n0 + rpl0) * K_DIM + cu0 * 8;
  const short* bG1 = wB   + (size_t)(n0 + rpl1) * K_DIM + cu1 * 8;
  char* aL0 = (char*)&As[0][0] + t * 16;
  char* aL1 = (char*)&As[0][0] + idx1 * 16;
  char* bL0 = (char*)&Bs[0][0] + t * 16;
  char* bL1 = (char*)&Bs[0][0] + idx1 * 16;

  auto stgA = [&](int ks, int h, int buf) {   // h,buf compile-time at call
    load_lds16(aG0 + h * (128 * K_DIM) + ks * 64, aL0 + buf * 32768 + h * 16384);
    load_lds16(aG1 + h * (128 * K_DIM) + ks * 64, aL1 + buf * 32768 + h * 16384);
  };
  auto stgB = [&](int ks, int h, int buf) {
    load_lds16(bG0 + h * (128 * K_DIM) + ks * 64, bL0 + buf * 32768 + h * 16384);
    load_lds16(bG1 + h * (128 * K_DIM) + ks * 64, bL1 + buf * 32768 + h * 16384);
  };

  // ---- fragment read bases: row r byte = r*128, chunk = (s*4+q)^(r&7) ----
  int cc0 = (q ^ (cl & 7)) * 16;
  const char* aRd0 = (const char*)&As[0][0] + wm * 16384 + cl * 128 + cc0;
  const char* aRd1 = (const char*)&As[0][0] + wm * 16384 + cl * 128 + (cc0 ^ 64);
  const char* bRd0 = (const char*)&Bs[0][0] + wn * 8192 + cl * 128 + cc0;
  const char* bRd1 = (const char*)&Bs[0][0] + wn * 8192 + cl * 128 + (cc0 ^ 64);

  auto rdA = [&](int buf, int mi, int s) -> bf16x8 {   // all args compile-time
    return *(const bf16x8*)((s ? aRd1 : aRd0) + buf * 32768 + mi * 2048);
  };
  auto rdB = [&](int buf, int ni, int s) -> bf16x8 {
    return *(const bf16x8*)((s ? bRd1 : bRd0) + buf * 32768 + ni * 2048);
  };

  f32x4 zero = {0.f, 0.f, 0.f, 0.f};
  f32x4 acc[8][4];
  #pragma unroll
  for (int mi = 0; mi < 8; ++mi)
    #pragma unroll
    for (int ni = 0; ni < 4; ++ni) acc[mi][ni] = zero;

  bf16x8 aLo[4][2], aHi[4][2], b0f[2][2], b1f[2][2];

  auto QUAD = [&](bf16x8 (&af)[4][2], bf16x8 (&bf)[2][2], int mb, int nb) {
    __builtin_amdgcn_s_setprio(1);
    #pragma unroll
    for (int mi = 0; mi < 4; ++mi)
      #pragma unroll
      for (int ni = 0; ni < 2; ++ni)
        #pragma unroll
        for (int s = 0; s < 2; ++s)
          acc[mb + mi][nb + ni] = __builtin_amdgcn_mfma_f32_16x16x32_bf16(
              af[mi][s], bf[ni][s], acc[mb + mi][nb + ni], 0, 0, 0);
    __builtin_amdgcn_s_setprio(0);
  };

  // One K-step (4 phases). bufC = current buffer; bufN = next K-step's buffer.
  // b0f for THIS step was preloaded in the previous P_d (or prologue).
  auto halfK = [&](int bufC, int bufN, int ksA_, int bufA_, int ksB_, int bufB_) {
    // -- P_a: read A-lo(8); stage A-h0; Q00 --
    #pragma unroll
    for (int mi = 0; mi < 4; ++mi) {
      aLo[mi][0] = rdA(bufC, mi, 0); aLo[mi][1] = rdA(bufC, mi, 1);
    }
    stgA(ksA_, 0, bufA_);
    asm volatile("s_waitcnt lgkmcnt(8)" ::: "memory");
    __builtin_amdgcn_s_barrier();
    asm volatile("s_waitcnt lgkmcnt(0)" ::: "memory");
    __builtin_amdgcn_sched_barrier(0);
    QUAD(aLo, b0f, 0, 0);
    __builtin_amdgcn_s_barrier();
    // -- P_b: read B1(4); stage A-h1; Q01 --
    #pragma unroll
    for (int ni = 0; ni < 2; ++ni) {
      b1f[ni][0] = rdB(bufC, ni + 2, 0); b1f[ni][1] = rdB(bufC, ni + 2, 1);
    }
    stgA(ksA_, 1, bufA_);
    __builtin_amdgcn_s_barrier();
    asm volatile("s_waitcnt lgkmcnt(0)" ::: "memory");
    __builtin_amdgcn_sched_barrier(0);
    QUAD(aLo, b1f, 0, 2);
    __builtin_amdgcn_s_barrier();
    // -- P_c: read A-hi(8); stage B-h0; Q11 --
    #pragma unroll
    for (int mi = 0; mi < 4; ++mi) {
      aHi[mi][0] = rdA(bufC, mi + 4, 0); aHi[mi][1] = rdA(bufC, mi + 4, 1);
    }
    stgB(ksB_, 0, bufB_);
    __builtin_amdgcn_s_barrier();
    asm volatile("s_waitcnt lgkmcnt(0)" ::: "memory");
    __builtin_amdgcn_sched_barrier(0);
    QUAD(aHi, b1f, 4, 2);
    __builtin_amdgcn_s_barrier();
    // -- P_d: stage B-h1; vmcnt(4) publishes bufN; Q10; preload next b0 --
    stgB(ksB_, 1, bufB_);
    asm volatile("s_waitcnt vmcnt(4)" ::: "memory");
    __builtin_amdgcn_s_barrier();
    __builtin_amdgcn_sched_barrier(0);
    QUAD(aHi, b0f, 4, 0);
    // b0 for next K-step from bufN (published above); WAR on b0f regs
    // orders these reads after Q10's MFMAs; barriers fence them in-phase.
    #pragma unroll
    for (int ni = 0; ni < 2; ++ni) {
      b0f[ni][0] = rdB(bufN, ni, 0); b0f[ni][1] = rdB(bufN, ni, 1);
    }
    __builtin_amdgcn_s_barrier();
  };

  // prologue = virtual prev-iteration P3..P8: B(0), A(0), B(1); drain 8 oldest
  stgB(0, 0, 0); stgB(0, 1, 0);
  stgA(0, 0, 0); stgA(0, 1, 0);
  stgB(1, 0, 1); stgB(1, 1, 1);
  asm volatile("s_waitcnt vmcnt(4)" ::: "memory");
  __builtin_amdgcn_s_barrier();
  // preload b0 for K-step 0 (tile 0, buf0)
  #pragma unroll
  for (int ni = 0; ni < 2; ++ni) {
    b0f[ni][0] = rdB(0, ni, 0); b0f[ni][1] = rdB(0, ni, 1);
  }

  #pragma unroll 1
  for (int i = 0; i < NIT; ++i) {
    int ks1 = 2 * i + 1;
    int ksA = 2 * i + 2; if (ksA > NKS - 1) ksA = NKS - 1;
    int ksB = 2 * i + 3; if (ksB > NKS - 1) ksB = NKS - 1;
    halfK(0, 1, ks1, 1, ksA, 0);   // K-step 2i   (buf0); stage A(2i+1), B(2i+2)
    halfK(1, 0, ksA, 0, ksB, 1);   // K-step 2i+1 (buf1); stage A(2i+2), B(2i+3)
  }
  asm volatile("s_waitcnt vmcnt(0)" ::: "memory");

  // ---- epilogue: each lane holds i,f,g,o for the same (row, h) ----
  int hg = (nblk * 4 + wn) * 16 + cl;
  float vbi = bi_p[hg], vbf = bf_p[hg], vbg = bg_p[hg], vbo = bo_p[hg];
  int mbase = m0 + wm * 128;
  #pragma unroll
  for (int mi = 0; mi < 8; ++mi) {
    #pragma unroll
    for (int r = 0; r < 4; ++r) {
      int mg = mbase + mi * 16 + q * 4 + r;
      float pi = acc[mi][0][r] + vbi;
      float pf = acc[mi][1][r] + vbf;
      float pg = acc[mi][2][r] + vbg;
      float po = acc[mi][3][r] + vbo;
      float iv = 1.f / (1.f + __expf(-pi));
      float fv = 1.f / (1.f + __expf(-pf));
      float gv = 1.f - 2.f / (__expf(2.f * pg) + 1.f);
      float ov = 1.f / (1.f + __expf(-po));
      float cp = cprev[(size_t)mg * H_DIM + hg];
      float cv = fv * cp + iv * gv;
      float tc = 1.f - 2.f / (__expf(2.f * cv) + 1.f);
      out[(size_t)mg * H_DIM + hg] = cv;
      out[CH_OFF + (size_t)mg * H_DIM + hg] = ov * tc;
    }
  }
}

extern "C" void kernel_launch(void* const* d_in, const int* in_sizes, int n_in,
                              void* d_out, int out_size, void* d_ws, size_t ws_size,
                              hipStream_t stream) {
  const float* inp   = (const float*)d_in[0];
  const float* hid   = (const float*)d_in[1];
  const float* cprev = (const float*)d_in[2];
  short* actB = (short*)d_ws;
  short* wB   = actB + (size_t)B_ROWS * K_DIM;

  pack_act<<<dim3(B_ROWS * K_DIM / 8 / 256), dim3(256), 0, stream>>>(inp, hid, actB);
  pack_w<<<dim3(8 * 1024), dim3(256), 0, stream>>>(
      (const float*)d_in[3], (const float*)d_in[4],
      (const float*)d_in[5], (const float*)d_in[6],
      (const float*)d_in[7], (const float*)d_in[8],
      (const float*)d_in[9], (const float*)d_in[10], wB);
  lstm_gemm<<<dim3(1024), dim3(512), 0, stream>>>(
      actB, wB, cprev,
      (const float*)d_in[11], (const float*)d_in[12],
      (const float*)d_in[13], (const float*)d_in[14],
      (float*)d_out);
}